// Round 3
// baseline (373.710 us; speedup 1.0000x reference)
//
#include <hip/hip_runtime.h>
#include <hip/hip_bf16.h>

typedef __attribute__((ext_vector_type(8))) short bf16x8;
typedef __attribute__((ext_vector_type(4))) float f32x4;
typedef unsigned short u16;
typedef unsigned int u32;

__device__ __forceinline__ u32 bf16_rne(float f) {
  u32 u = __float_as_uint(f);
  return (u + 0x7FFFu + ((u >> 16) & 1u)) >> 16;
}
__device__ __forceinline__ float bf16_val(u32 b) { return __uint_as_float(b << 16); }

__device__ __forceinline__ void g2l16(const u16* g, u16* l) {
  __builtin_amdgcn_global_load_lds(
      (const __attribute__((address_space(1))) u32*)g,
      (__attribute__((address_space(3))) u32*)l, 16, 0, 0);
}

// ---- split fp32 array into bf16 hi/lo (no transpose) ----
__global__ void split_arr(const float* __restrict__ in,
                          u16* __restrict__ hi, u16* __restrict__ lo, int n4) {
  int i = blockIdx.x * 256 + threadIdx.x;
  if (i >= n4) return;
  float4 v = ((const float4*)in)[i];
  u32 h0 = bf16_rne(v.x), h1 = bf16_rne(v.y), h2 = bf16_rne(v.z), h3 = bf16_rne(v.w);
  u32 l0 = bf16_rne(v.x - bf16_val(h0));
  u32 l1 = bf16_rne(v.y - bf16_val(h1));
  u32 l2 = bf16_rne(v.z - bf16_val(h2));
  u32 l3 = bf16_rne(v.w - bf16_val(h3));
  ushort4 hv; hv.x = (u16)h0; hv.y = (u16)h1; hv.z = (u16)h2; hv.w = (u16)h3;
  ushort4 lv; lv.x = (u16)l0; lv.y = (u16)l1; lv.z = (u16)l2; lv.w = (u16)l3;
  ((ushort4*)hi)[i] = hv;
  ((ushort4*)lo)[i] = lv;
}

// ---- transpose each 256x256 fp32 slice and split into bf16 hi/lo arrays ----
__global__ void split_transpose256(const float* __restrict__ in,
                                   u16* __restrict__ hi, u16* __restrict__ lo) {
  __shared__ float tile[32][33];
  const size_t off = (size_t)blockIdx.z * 65536;
  const int tx = threadIdx.x, ty = threadIdx.y;
#pragma unroll
  for (int i = 0; i < 4; ++i) {
    int y = blockIdx.y * 32 + ty + i * 8;
    int x = blockIdx.x * 32 + tx;
    tile[ty + i * 8][tx] = in[off + (size_t)y * 256 + x];
  }
  __syncthreads();
#pragma unroll
  for (int i = 0; i < 4; ++i) {
    float v = tile[tx][ty + i * 8];
    u32 hb = bf16_rne(v);
    u32 lb = bf16_rne(v - bf16_val(hb));
    size_t idx = off + (size_t)(blockIdx.x * 32 + ty + i * 8) * 256 + blockIdx.y * 32 + tx;
    hi[idx] = (u16)hb;
    lo[idx] = (u16)lb;
  }
}

// ---------------- fused priors-GEMM (split-bf16) + dynamic routing ----------------
// M = 256 rows per block = APB independent routings of R rows each.
// 512 threads = 8 waves, wave grid mg(2) x eg(4); per-wave tile 128 rows x 64 cols,
// acc[8][4] f32x4 = 128 regs; __launch_bounds__(512,2) -> 256-reg budget.
// Row r = mg*128 + mt*16 + q*4 + rr; col e = eg*64 + ct*16 + li.
// GEMM: double-buffered 64KB k-slices, counted s_waitcnt vmcnt(8) + raw s_barrier.
// A-fragment ping-pong prefetch (read mt+1 before mt's MFMAs) hides ds_read
// latency under the MFMA cluster (round-2 counters showed LDS+MFMA additive).
// LDS k-granule XOR swizzle (verified 0 conflicts): DMA source pre-swizzled
// (linear LDS dest), readers pick slot q ^ ((li>>1)&3).
// Routing: all-wave redundant softmax (each wave computes probs for its own
// 128 rows -> no probs barrier, no idle waves).
template <int R>
__global__ __launch_bounds__(512, 2) void caps_route(
    const u16* __restrict__ Ahi_g,   // [blocks][256 rows][256] bf16-hi
    const u16* __restrict__ Alo_g,
    const u16* __restrict__ Whi,     // [KN][256][256] (transposed [e][d])
    const u16* __restrict__ Wlo,
    u16* __restrict__ o1hi, u16* __restrict__ o1lo,   // stage1 out (split)
    float* __restrict__ outp,                          // stage2 out
    int KN, int stage) {
  constexpr int APB = 256 / R;              // routings (a's) per block
  constexpr int SEG = APB / 2;              // row-segments per wave (1 or 2)
  constexpr int MTS = 8 / SEG;              // m-tiles per segment
  constexpr int ABS = (R == 128) ? 5 : 4;   // log2(a-blocks in grid)
  __shared__ u16 BUF[2][32768];             // dbuf: [Ahi|Alo|Whi|Wlo] x 16 chunks x 512 u16
  __shared__ __align__(16) float wlog[4][256];
  __shared__ __align__(16) float probs[256];
  __shared__ float sqpart[4][4];

  const int tid = threadIdx.x;
  const int w = tid >> 6, lane = tid & 63, q = lane >> 4, li = lane & 15;
  const int mg = w >> 2, eg = w & 3;        // mg 0..1, eg 0..3
  const int kk = blockIdx.x >> ABS;         // weight slice (h or c)
  const int ab = blockIdx.x & ((1 << ABS) - 1);

  // ---- staging: wave w stages row-blocks {w, w+8} of each of the 4 arrays ----
  const int sub = lane >> 2, p = lane & 3;
  const int gslot = p ^ ((sub >> 1) & 3);              // pre-swizzled k-granule
  const size_t goff = (size_t)w * 4096 + sub * 256 + gslot * 8;
  const u16* gAh = Ahi_g + (size_t)ab * 65536 + goff;
  const u16* gAl = Alo_g + (size_t)ab * 65536 + goff;
  const u16* gWh = Whi  + (size_t)kk * 65536 + goff;
  const u16* gWl = Wlo  + (size_t)kk * 65536 + goff;
  u16* l0 = &BUF[0][0] + w * 512 + lane * 8;           // linear LDS dest (DMA rule)
  u16* l1 = &BUF[1][0] + w * 512 + lane * 8;

#define STAGE8(ko, l)                          \
  do {                                         \
    g2l16(gAh + (ko), (l));                    \
    g2l16(gAh + (ko) + 32768, (l) + 4096);     \
    g2l16(gAl + (ko), (l) + 8192);             \
    g2l16(gAl + (ko) + 32768, (l) + 12288);    \
    g2l16(gWh + (ko), (l) + 16384);            \
    g2l16(gWh + (ko) + 32768, (l) + 20480);    \
    g2l16(gWl + (ko), (l) + 24576);            \
    g2l16(gWl + (ko) + 32768, (l) + 28672);    \
  } while (0)

  // ---- fragment read offset (swizzled slot) ----
  const int rslot = q ^ ((li >> 1) & 3);
  const int fbase = li * 32 + rslot * 8;               // u16 units within a chunk

  f32x4 acc[8][4] = {};

  STAGE8(0, l0);                                       // prologue: slice 0 -> buf 0

  // ---- GEMM main loop: P = A (256 x 256) @ W[kk] (256 x 256), split-bf16 3-MFMA ----
#pragma unroll
  for (int ks = 0; ks < 8; ++ks) {
    const u16* B0 = (ks & 1) ? &BUF[1][0] : &BUF[0][0];
    if (ks < 7) {
      const int ko = (ks + 1) * 32;                    // next k-slice, u16 units
      if (ks & 1) STAGE8(ko, l0); else STAGE8(ko, l1);
      asm volatile("s_waitcnt vmcnt(8)" ::: "memory"); // current 8 landed; next 8 in flight
    } else {
      asm volatile("s_waitcnt vmcnt(0)" ::: "memory");
    }
    __builtin_amdgcn_s_barrier();
    asm volatile("" ::: "memory");
    bf16x8 bh[4], bl[4];
#pragma unroll
    for (int ct = 0; ct < 4; ++ct) {
      const u16* bp = B0 + 16384 + (eg * 4 + ct) * 512 + fbase;
      bh[ct] = *(const bf16x8*)bp;
      bl[ct] = *(const bf16x8*)(bp + 8192);
    }
    // A-fragment ping-pong: request mt+1 before mt's MFMA cluster
    const u16* aB = B0 + mg * 4096 + fbase;
    bf16x8 ahc = *(const bf16x8*)(aB);
    bf16x8 alc = *(const bf16x8*)(aB + 8192);
#pragma unroll
    for (int mt = 0; mt < 8; ++mt) {
      bf16x8 ahn, aln;
      if (mt < 7) {
        ahn = *(const bf16x8*)(aB + (mt + 1) * 512);
        aln = *(const bf16x8*)(aB + (mt + 1) * 512 + 8192);
      }
      __builtin_amdgcn_s_setprio(1);
#pragma unroll
      for (int ct = 0; ct < 4; ++ct)
        acc[mt][ct] = __builtin_amdgcn_mfma_f32_16x16x32_bf16(alc, bh[ct], acc[mt][ct], 0, 0, 0);
#pragma unroll
      for (int ct = 0; ct < 4; ++ct)
        acc[mt][ct] = __builtin_amdgcn_mfma_f32_16x16x32_bf16(ahc, bl[ct], acc[mt][ct], 0, 0, 0);
#pragma unroll
      for (int ct = 0; ct < 4; ++ct)
        acc[mt][ct] = __builtin_amdgcn_mfma_f32_16x16x32_bf16(ahc, bh[ct], acc[mt][ct], 0, 0, 0);
      __builtin_amdgcn_s_setprio(0);
      if (mt < 7) { ahc = ahn; alc = aln; }
    }
    asm volatile("" ::: "memory");
    __builtin_amdgcn_s_barrier();                      // protect buffer reuse next iter
  }
#undef STAGE8

  // ---- dynamic routing (3 iterations), APB independent routings ----
  // Wave (mg,eg) owns rows mg*128..+127 = segments a = mg*SEG + sg (wave-local).
  const float invR = 1.0f / R;
  const int rb = mg * 128;                             // wave's global row base
  float v[SEG][4];
  float lg0 = 0.f, lg1 = 0.f;                          // running logits (all waves)

  for (int iter = 0; iter < 3; ++iter) {
    // hoisted probs fragments for this wave's rows
    float4 p4[8];
    if (iter == 0) {
#pragma unroll
      for (int mt = 0; mt < 8; ++mt) {
        p4[mt].x = invR; p4[mt].y = invR; p4[mt].z = invR; p4[mt].w = invR;
      }
    } else {
#pragma unroll
      for (int mt = 0; mt < 8; ++mt)
        p4[mt] = *(const float4*)&probs[rb + mt * 16 + q * 4];
    }
    // s[a][e] = sum_b probs[b] * P[b,e] : in-lane over (mt,rr), shfl over q
    float s[SEG][4];
#pragma unroll
    for (int sg = 0; sg < SEG; ++sg) {
#pragma unroll
      for (int ct = 0; ct < 4; ++ct) {
        float t = 0.f;
#pragma unroll
        for (int mi = 0; mi < MTS; ++mi) {
          const int mt = sg * MTS + mi;
          t += p4[mt].x * acc[mt][ct][0] + p4[mt].y * acc[mt][ct][1] +
               p4[mt].z * acc[mt][ct][2] + p4[mt].w * acc[mt][ct][3];
        }
        t += __shfl_xor(t, 16);
        t += __shfl_xor(t, 32);
        s[sg][ct] = t;
      }
    }
    // squash: sq_a = sum_e s_a[e]^2 over 256 e (LDS over eg)
#pragma unroll
    for (int sg = 0; sg < SEG; ++sg) {
      float ss = s[sg][0] * s[sg][0] + s[sg][1] * s[sg][1] +
                 s[sg][2] * s[sg][2] + s[sg][3] * s[sg][3];
      ss += __shfl_xor(ss, 1); ss += __shfl_xor(ss, 2);
      ss += __shfl_xor(ss, 4); ss += __shfl_xor(ss, 8);
      if (lane == 0) sqpart[mg * SEG + sg][eg] = ss;
    }
    __syncthreads();
#pragma unroll
    for (int sg = 0; sg < SEG; ++sg) {
      const int a = mg * SEG + sg;
      float sq = sqpart[a][0] + sqpart[a][1] + sqpart[a][2] + sqpart[a][3];
      float scale = (sq > 0.f) ? sq / ((1.0f + sq) * sqrtf(sq)) : 0.f;
#pragma unroll
      for (int ct = 0; ct < 4; ++ct) v[sg][ct] = s[sg][ct] * scale;
    }

    if (iter < 2) {
      // logits[b] += sum_e P[b,e] * v[a(b)][e] : in-lane over ct, shfl over li, LDS over eg
#pragma unroll
      for (int mt = 0; mt < 8; ++mt) {
        const int sg = mt / MTS;
        float tt[4];
#pragma unroll
        for (int rr = 0; rr < 4; ++rr) {
          float t = acc[mt][0][rr] * v[sg][0] + acc[mt][1][rr] * v[sg][1] +
                    acc[mt][2][rr] * v[sg][2] + acc[mt][3][rr] * v[sg][3];
          t += __shfl_xor(t, 1); t += __shfl_xor(t, 2);
          t += __shfl_xor(t, 4); t += __shfl_xor(t, 8);
          tt[rr] = t;
        }
        if (li == 0)
          *(float4*)&wlog[eg][rb + mt * 16 + q * 4] =
              make_float4(tt[0], tt[1], tt[2], tt[3]);
      }
      __syncthreads();
      // all-wave softmax: every wave computes probs for ITS OWN 128 rows.
      // (4 eg-waves write identical values to the same addresses: benign.)
      // No barrier needed after: each wave reads back only what it wrote.
      if (R == 128) {
        int r0 = rb + lane, r1 = r0 + 64;   // one routing (a = mg) over 128 rows
        lg0 += wlog[0][r0] + wlog[1][r0] + wlog[2][r0] + wlog[3][r0];
        lg1 += wlog[0][r1] + wlog[1][r1] + wlog[2][r1] + wlog[3][r1];
        float m = fmaxf(lg0, lg1);
#pragma unroll
        for (int d2 = 1; d2 < 64; d2 <<= 1) m = fmaxf(m, __shfl_xor(m, d2));
        float e0 = __expf(lg0 - m), e1 = __expf(lg1 - m);
        float zz = e0 + e1;
#pragma unroll
        for (int d2 = 1; d2 < 64; d2 <<= 1) zz += __shfl_xor(zz, d2);
        float inv = 1.0f / zz;
        probs[r0] = e0 * inv;
        probs[r1] = e1 * inv;
      } else {
        int r0 = rb + lane, r1 = r0 + 64;   // two routings (a = 2mg, 2mg+1), 64 rows each
        lg0 += wlog[0][r0] + wlog[1][r0] + wlog[2][r0] + wlog[3][r0];
        lg1 += wlog[0][r1] + wlog[1][r1] + wlog[2][r1] + wlog[3][r1];
        float m0 = lg0, m1 = lg1;
#pragma unroll
        for (int d2 = 1; d2 < 64; d2 <<= 1) {
          m0 = fmaxf(m0, __shfl_xor(m0, d2));
          m1 = fmaxf(m1, __shfl_xor(m1, d2));
        }
        float e0 = __expf(lg0 - m0), e1 = __expf(lg1 - m1);
        float z0 = e0, z1 = e1;
#pragma unroll
        for (int d2 = 1; d2 < 64; d2 <<= 1) {
          z0 += __shfl_xor(z0, d2);
          z1 += __shfl_xor(z1, d2);
        }
        probs[r0] = e0 / z0;
        probs[r1] = e1 / z1;
      }
      asm volatile("s_waitcnt lgkmcnt(0)" ::: "memory");  // writes land before next-iter reads
    }
  }

  // ---- epilogue. stage1 -> split out1[a][kk][e]; stage2 -> fp32 out[kk][a][e] ----
  if (q == 0) {
#pragma unroll
    for (int sg = 0; sg < SEG; ++sg) {
      const int ag = ab * APB + mg * SEG + sg;   // global a
      if (stage == 1) {
        size_t ob = ((size_t)ag * KN + kk) * 256;
#pragma unroll
        for (int ct = 0; ct < 4; ++ct) {
          int e = eg * 64 + ct * 16 + li;
          u32 hb = bf16_rne(v[sg][ct]);
          u32 lb = bf16_rne(v[sg][ct] - bf16_val(hb));
          o1hi[ob + e] = (u16)hb;
          o1lo[ob + e] = (u16)lb;
        }
      } else {
        size_t ob = ((size_t)kk * 64 + ag) * 256;
#pragma unroll
        for (int ct = 0; ct < 4; ++ct) {
          int e = eg * 64 + ct * 16 + li;
          outp[ob + e] = v[sg][ct];
        }
      }
    }
  }
}

extern "C" void kernel_launch(void* const* d_in, const int* in_sizes, int n_in,
                              void* d_out, int out_size, void* d_ws, size_t ws_size,
                              hipStream_t stream) {
  const float* x  = (const float*)d_in[0];   // [64][128][256]
  const float* w1 = (const float*)d_in[1];   // [64][256][256]
  const float* wc = (const float*)d_in[2];   // [32][256][256]
  float* out = (float*)d_out;                // [32][64][256]

  char* ws = (char*)d_ws;
  u16* w1hi = (u16*)(ws);                    // 8 MB
  u16* w1lo = (u16*)(ws + (8u << 20));       // 8 MB
  u16* wchi = (u16*)(ws + (16u << 20));      // 4 MB
  u16* wclo = (u16*)(ws + (20u << 20));      // 4 MB
  u16* xhi  = (u16*)(ws + (24u << 20));      // 4 MB
  u16* xlo  = (u16*)(ws + (28u << 20));      // 4 MB
  u16* o1hi = (u16*)(ws + (32u << 20));      // 2 MB
  u16* o1lo = (u16*)(ws + (34u << 20));      // 2 MB

  split_arr<<<2048, 256, 0, stream>>>(x, xhi, xlo, 524288);
  split_transpose256<<<dim3(8, 8, 64), dim3(32, 8), 0, stream>>>(w1, w1hi, w1lo);
  split_transpose256<<<dim3(8, 8, 32), dim3(32, 8), 0, stream>>>(wc, wchi, wclo);
  // stage 1: 64 kk x 32 a-pairs, M=256 (2 a's of R=128)
  caps_route<128><<<64 * 32, 512, 0, stream>>>(xhi, xlo, w1hi, w1lo, o1hi, o1lo, nullptr, 64, 1);
  // stage 2: 32 kk x 16 a-quads, M=256 (4 a's of R=64)
  caps_route<64><<<32 * 16, 512, 0, stream>>>(o1hi, o1lo, wchi, wclo, nullptr, nullptr, out, 32, 2);
}

// Round 4
// 357.208 us; speedup vs baseline: 1.0462x; 1.0462x over previous
//
#include <hip/hip_runtime.h>
#include <hip/hip_bf16.h>

typedef __attribute__((ext_vector_type(8))) short bf16x8;
typedef __attribute__((ext_vector_type(4))) float f32x4;
typedef unsigned short u16;
typedef unsigned int u32;

__device__ __forceinline__ u32 bf16_rne(float f) {
  u32 u = __float_as_uint(f);
  return (u + 0x7FFFu + ((u >> 16) & 1u)) >> 16;
}
__device__ __forceinline__ float bf16_val(u32 b) { return __uint_as_float(b << 16); }

__device__ __forceinline__ void g2l16(const u16* g, u16* l) {
  __builtin_amdgcn_global_load_lds(
      (const __attribute__((address_space(1))) u32*)g,
      (__attribute__((address_space(3))) u32*)l, 16, 0, 0);
}

// ---- split fp32 array into bf16 hi/lo (no transpose) ----
__global__ void split_arr(const float* __restrict__ in,
                          u16* __restrict__ hi, u16* __restrict__ lo, int n4) {
  int i = blockIdx.x * 256 + threadIdx.x;
  if (i >= n4) return;
  float4 v = ((const float4*)in)[i];
  u32 h0 = bf16_rne(v.x), h1 = bf16_rne(v.y), h2 = bf16_rne(v.z), h3 = bf16_rne(v.w);
  u32 l0 = bf16_rne(v.x - bf16_val(h0));
  u32 l1 = bf16_rne(v.y - bf16_val(h1));
  u32 l2 = bf16_rne(v.z - bf16_val(h2));
  u32 l3 = bf16_rne(v.w - bf16_val(h3));
  ushort4 hv; hv.x = (u16)h0; hv.y = (u16)h1; hv.z = (u16)h2; hv.w = (u16)h3;
  ushort4 lv; lv.x = (u16)l0; lv.y = (u16)l1; lv.z = (u16)l2; lv.w = (u16)l3;
  ((ushort4*)hi)[i] = hv;
  ((ushort4*)lo)[i] = lv;
}

// ---- transpose each 256x256 fp32 slice and split into bf16 hi/lo arrays ----
__global__ void split_transpose256(const float* __restrict__ in,
                                   u16* __restrict__ hi, u16* __restrict__ lo) {
  __shared__ float tile[32][33];
  const size_t off = (size_t)blockIdx.z * 65536;
  const int tx = threadIdx.x, ty = threadIdx.y;
#pragma unroll
  for (int i = 0; i < 4; ++i) {
    int y = blockIdx.y * 32 + ty + i * 8;
    int x = blockIdx.x * 32 + tx;
    tile[ty + i * 8][tx] = in[off + (size_t)y * 256 + x];
  }
  __syncthreads();
#pragma unroll
  for (int i = 0; i < 4; ++i) {
    float v = tile[tx][ty + i * 8];
    u32 hb = bf16_rne(v);
    u32 lb = bf16_rne(v - bf16_val(hb));
    size_t idx = off + (size_t)(blockIdx.x * 32 + ty + i * 8) * 256 + blockIdx.y * 32 + tx;
    hi[idx] = (u16)hb;
    lo[idx] = (u16)lb;
  }
}

// ---------------- fused priors-GEMM (split-bf16) + dynamic routing ----------------
// ROUND-4 STRUCTURE: M=128 rows per block, 256 threads = 4 waves (pure eg roles),
// per-wave tile 128x64 (acc[8][4] = 128 regs), __launch_bounds__(256,2) ->
// TWO independent blocks per CU (LDS ~67KB each). Rationale: round-2/3 counters
// showed phase serialization (one resident block: MFMA idle during routing,
// VALU idle during GEMM). Two out-of-phase blocks fill each other's pipes (m114).
// Row r = mt*16 + q*4 + rr (all rows in every wave); col e = eg*64 + ct*16 + li.
// GEMM: A double-buffered (2x16KB), W single-buffered (32KB) but register-staged
// (8 bf16x8 read BEFORE next DMA overwrites) -> full 48KB/step DMA overlaps MFMAs.
// LDS k-granule XOR swizzle (0 conflicts, verified): DMA source pre-swizzled
// (linear LDS dest), readers pick slot q ^ ((li>>1)&3).
template <int R>
__global__ __launch_bounds__(256, 2) void caps_route(
    const u16* __restrict__ Ahi_g,   // [ab][128 rows][256] bf16-hi
    const u16* __restrict__ Alo_g,
    const u16* __restrict__ Whi,     // [KN][256][256] (transposed [e][d])
    const u16* __restrict__ Wlo,
    u16* __restrict__ o1hi, u16* __restrict__ o1lo,   // stage1 out (split)
    float* __restrict__ outp,                          // stage2 out
    int KN, int stage) {
  constexpr int APB = 128 / R;              // routings per block (1 or 2)
  constexpr int SEG = APB;                  // segments per wave (all rows wave-local)
  constexpr int MTS = 8 / SEG;              // m-tiles per segment
  constexpr int ABS = (R == 128) ? 6 : 5;   // log2(a-blocks in grid)
  __shared__ __align__(16) u16 Ab[2][8192];  // A dbuf: [Ahi(8KB) | Alo(8KB)] per slice
  __shared__ __align__(16) u16 Wb[16384];    // W single buf: [Whi(16KB) | Wlo(16KB)]
  __shared__ __align__(16) float wlog[4][128];
  __shared__ __align__(16) float probs[128];
  __shared__ float sqpart[2][4];

  const int tid = threadIdx.x;
  const int w = tid >> 6, lane = tid & 63, q = lane >> 4, li = lane & 15;
  const int eg = w;                         // wave = column group
  const int kk = blockIdx.x >> ABS;         // weight slice (h or c)
  const int ab = blockIdx.x & ((1 << ABS) - 1);

  // ---- staging roles: w0 -> W-hi (16 chunks), w1 -> W-lo (16), w2 -> A-hi (8), w3 -> A-lo (8)
  const int sub = lane >> 2, p = lane & 3;
  const int gslot = p ^ ((sub >> 1) & 3);              // pre-swizzled k-granule
  const size_t lane_off = (size_t)sub * 256 + gslot * 8;
  const u16* gsrc;
  u16* ldst;
  if (w == 0)      { gsrc = Whi   + (size_t)kk * 65536 + lane_off; ldst = &Wb[0]       + lane * 8; }
  else if (w == 1) { gsrc = Wlo   + (size_t)kk * 65536 + lane_off; ldst = &Wb[8192]    + lane * 8; }
  else if (w == 2) { gsrc = Ahi_g + (size_t)ab * 32768 + lane_off; ldst = &Ab[0][0]    + lane * 8; }
  else             { gsrc = Alo_g + (size_t)ab * 32768 + lane_off; ldst = &Ab[0][4096] + lane * 8; }

  auto STAGE = [&](int ko, int nb) {
    if (w < 2) {
#pragma unroll
      for (int i = 0; i < 16; ++i) g2l16(gsrc + ko + i * 4096, ldst + i * 512);
    } else {
      u16* d = ldst + nb * 8192;
#pragma unroll
      for (int i = 0; i < 8; ++i) g2l16(gsrc + ko + i * 4096, d + i * 512);
    }
  };

  // ---- fragment read offset (swizzled slot) ----
  const int rslot = q ^ ((li >> 1) & 3);
  const int fbase = li * 32 + rslot * 8;               // u16 units within a chunk

  f32x4 acc[8][4] = {};

  STAGE(0, 0);                                         // prologue: slice 0
  asm volatile("s_waitcnt vmcnt(0)" ::: "memory");
  __builtin_amdgcn_s_barrier();

  // ---- GEMM main loop: P = A (128 x 256) @ W[kk] (256 x 256), split-bf16 3-MFMA ----
#pragma unroll
  for (int ks = 0; ks < 8; ++ks) {
    // W frags for slice ks -> registers (before Wb is overwritten)
    bf16x8 bh[4], bl[4];
#pragma unroll
    for (int ct = 0; ct < 4; ++ct) {
      const u16* bp = &Wb[(eg * 4 + ct) * 512] + fbase;
      bh[ct] = *(const bf16x8*)bp;
      bl[ct] = *(const bf16x8*)(bp + 8192);
    }
    asm volatile("s_waitcnt lgkmcnt(0)" ::: "memory"); // all W reads done...
    __builtin_amdgcn_s_barrier();                      // ...in every wave
    if (ks < 7) STAGE((ks + 1) * 32, (ks + 1) & 1);    // DMA next slice (overlaps MFMAs)
    const u16* aB = &Ab[ks & 1][0] + fbase;
#pragma unroll
    for (int mt = 0; mt < 8; ++mt) {
      bf16x8 ah = *(const bf16x8*)(aB + mt * 512);
      bf16x8 al = *(const bf16x8*)(aB + mt * 512 + 4096);
#pragma unroll
      for (int ct = 0; ct < 4; ++ct) {
        acc[mt][ct] = __builtin_amdgcn_mfma_f32_16x16x32_bf16(al, bh[ct], acc[mt][ct], 0, 0, 0);
        acc[mt][ct] = __builtin_amdgcn_mfma_f32_16x16x32_bf16(ah, bl[ct], acc[mt][ct], 0, 0, 0);
        acc[mt][ct] = __builtin_amdgcn_mfma_f32_16x16x32_bf16(ah, bh[ct], acc[mt][ct], 0, 0, 0);
      }
    }
    asm volatile("s_waitcnt vmcnt(0)" ::: "memory");   // next slice landed
    __builtin_amdgcn_s_barrier();
  }

  // ---- dynamic routing (3 iterations), APB independent routings, all wave-local ----
  const float invR = 1.0f / R;
  float v[SEG][4];
  float lg0 = 0.f, lg1 = 0.f;                          // running logits (all waves)

  for (int iter = 0; iter < 3; ++iter) {
    float4 p4[8];
    if (iter == 0) {
#pragma unroll
      for (int mt = 0; mt < 8; ++mt) {
        p4[mt].x = invR; p4[mt].y = invR; p4[mt].z = invR; p4[mt].w = invR;
      }
    } else {
#pragma unroll
      for (int mt = 0; mt < 8; ++mt)
        p4[mt] = *(const float4*)&probs[mt * 16 + q * 4];
    }
    // s[a][e] = sum_b probs[b] * P[b,e] : in-lane over (mt,rr), shfl over q
    float s[SEG][4];
#pragma unroll
    for (int sg = 0; sg < SEG; ++sg) {
#pragma unroll
      for (int ct = 0; ct < 4; ++ct) {
        float t = 0.f;
#pragma unroll
        for (int mi = 0; mi < MTS; ++mi) {
          const int mt = sg * MTS + mi;
          t += p4[mt].x * acc[mt][ct][0] + p4[mt].y * acc[mt][ct][1] +
               p4[mt].z * acc[mt][ct][2] + p4[mt].w * acc[mt][ct][3];
        }
        t += __shfl_xor(t, 16);
        t += __shfl_xor(t, 32);
        s[sg][ct] = t;
      }
    }
    // squash: sq_a = sum_e s_a[e]^2 over 256 e (LDS over eg)
#pragma unroll
    for (int sg = 0; sg < SEG; ++sg) {
      float ss = s[sg][0] * s[sg][0] + s[sg][1] * s[sg][1] +
                 s[sg][2] * s[sg][2] + s[sg][3] * s[sg][3];
      ss += __shfl_xor(ss, 1); ss += __shfl_xor(ss, 2);
      ss += __shfl_xor(ss, 4); ss += __shfl_xor(ss, 8);
      if (lane == 0) sqpart[sg][eg] = ss;
    }
    __syncthreads();
#pragma unroll
    for (int sg = 0; sg < SEG; ++sg) {
      float sq = sqpart[sg][0] + sqpart[sg][1] + sqpart[sg][2] + sqpart[sg][3];
      float scale = (sq > 0.f) ? sq / ((1.0f + sq) * sqrtf(sq)) : 0.f;
#pragma unroll
      for (int ct = 0; ct < 4; ++ct) v[sg][ct] = s[sg][ct] * scale;
    }

    if (iter < 2) {
      // logits[b] += sum_e P[b,e] * v[a(b)][e] : in-lane over ct, shfl over li, LDS over eg
#pragma unroll
      for (int mt = 0; mt < 8; ++mt) {
        const int sg = mt / MTS;
        float tt[4];
#pragma unroll
        for (int rr = 0; rr < 4; ++rr) {
          float t = acc[mt][0][rr] * v[sg][0] + acc[mt][1][rr] * v[sg][1] +
                    acc[mt][2][rr] * v[sg][2] + acc[mt][3][rr] * v[sg][3];
          t += __shfl_xor(t, 1); t += __shfl_xor(t, 2);
          t += __shfl_xor(t, 4); t += __shfl_xor(t, 8);
          tt[rr] = t;
        }
        if (li == 0)
          *(float4*)&wlog[eg][mt * 16 + q * 4] = make_float4(tt[0], tt[1], tt[2], tt[3]);
      }
      __syncthreads();
      // all-wave redundant softmax (identical values; each wave reads its own writes)
      if (R == 128) {
        int r0 = lane, r1 = lane + 64;   // one routing over 128 rows
        lg0 += wlog[0][r0] + wlog[1][r0] + wlog[2][r0] + wlog[3][r0];
        lg1 += wlog[0][r1] + wlog[1][r1] + wlog[2][r1] + wlog[3][r1];
        float m = fmaxf(lg0, lg1);
#pragma unroll
        for (int d2 = 1; d2 < 64; d2 <<= 1) m = fmaxf(m, __shfl_xor(m, d2));
        float e0 = __expf(lg0 - m), e1 = __expf(lg1 - m);
        float zz = e0 + e1;
#pragma unroll
        for (int d2 = 1; d2 < 64; d2 <<= 1) zz += __shfl_xor(zz, d2);
        float inv = 1.0f / zz;
        probs[r0] = e0 * inv;
        probs[r1] = e1 * inv;
      } else {
        int r0 = lane, r1 = lane + 64;   // two routings (rows 0..63 = a0, 64..127 = a1)
        lg0 += wlog[0][r0] + wlog[1][r0] + wlog[2][r0] + wlog[3][r0];
        lg1 += wlog[0][r1] + wlog[1][r1] + wlog[2][r1] + wlog[3][r1];
        float m0 = lg0, m1 = lg1;
#pragma unroll
        for (int d2 = 1; d2 < 64; d2 <<= 1) {
          m0 = fmaxf(m0, __shfl_xor(m0, d2));
          m1 = fmaxf(m1, __shfl_xor(m1, d2));
        }
        float e0 = __expf(lg0 - m0), e1 = __expf(lg1 - m1);
        float z0 = e0, z1 = e1;
#pragma unroll
        for (int d2 = 1; d2 < 64; d2 <<= 1) {
          z0 += __shfl_xor(z0, d2);
          z1 += __shfl_xor(z1, d2);
        }
        probs[r0] = e0 / z0;
        probs[r1] = e1 / z1;
      }
      asm volatile("s_waitcnt lgkmcnt(0)" ::: "memory");  // writes land before next-iter reads
    }
  }

  // ---- epilogue. stage1 -> split out1[a][kk][e]; stage2 -> fp32 out[kk][a][e] ----
  if (q == 0) {
#pragma unroll
    for (int sg = 0; sg < SEG; ++sg) {
      const int ag = ab * APB + sg;      // global a
      if (stage == 1) {
        size_t ob = ((size_t)ag * KN + kk) * 256;
#pragma unroll
        for (int ct = 0; ct < 4; ++ct) {
          int e = eg * 64 + ct * 16 + li;
          u32 hb = bf16_rne(v[sg][ct]);
          u32 lb = bf16_rne(v[sg][ct] - bf16_val(hb));
          o1hi[ob + e] = (u16)hb;
          o1lo[ob + e] = (u16)lb;
        }
      } else {
        size_t ob = ((size_t)kk * 64 + ag) * 256;
#pragma unroll
        for (int ct = 0; ct < 4; ++ct) {
          int e = eg * 64 + ct * 16 + li;
          outp[ob + e] = v[sg][ct];
        }
      }
    }
  }
}

extern "C" void kernel_launch(void* const* d_in, const int* in_sizes, int n_in,
                              void* d_out, int out_size, void* d_ws, size_t ws_size,
                              hipStream_t stream) {
  const float* x  = (const float*)d_in[0];   // [64][128][256]
  const float* w1 = (const float*)d_in[1];   // [64][256][256]
  const float* wc = (const float*)d_in[2];   // [32][256][256]
  float* out = (float*)d_out;                // [32][64][256]

  char* ws = (char*)d_ws;
  u16* w1hi = (u16*)(ws);                    // 8 MB
  u16* w1lo = (u16*)(ws + (8u << 20));       // 8 MB
  u16* wchi = (u16*)(ws + (16u << 20));      // 4 MB
  u16* wclo = (u16*)(ws + (20u << 20));      // 4 MB
  u16* xhi  = (u16*)(ws + (24u << 20));      // 4 MB
  u16* xlo  = (u16*)(ws + (28u << 20));      // 4 MB
  u16* o1hi = (u16*)(ws + (32u << 20));      // 2 MB
  u16* o1lo = (u16*)(ws + (34u << 20));      // 2 MB

  split_arr<<<2048, 256, 0, stream>>>(x, xhi, xlo, 524288);
  split_transpose256<<<dim3(8, 8, 64), dim3(32, 8), 0, stream>>>(w1, w1hi, w1lo);
  split_transpose256<<<dim3(8, 8, 32), dim3(32, 8), 0, stream>>>(wc, wchi, wclo);
  // stage 1: 64 kk x 64 a-blocks (M=128 = 1 routing of R=128), 2 blocks/CU
  caps_route<128><<<64 * 64, 256, 0, stream>>>(xhi, xlo, w1hi, w1lo, o1hi, o1lo, nullptr, 64, 1);
  // stage 2: 32 kk x 32 a-blocks (M=128 = 2 routings of R=64), 2 blocks/CU
  caps_route<64><<<32 * 32, 256, 0, stream>>>(o1hi, o1lo, wchi, wclo, nullptr, nullptr, out, 32, 2);
}